// Round 2
// baseline (195.157 us; speedup 1.0000x reference)
//
#include <hip/hip_runtime.h>

// Scaled dot-product attention, B=2 S=2048 D=1024 H=16 dh=64, fp32 in/out.
// Flash-attention fwd, bf16 MFMA 16x16x32, fp32 accumulate.
// R2: M_TILE 64 (grid 1024 -> 4 blocks/CU by grid, 3 by LDS), 2 barriers/iter,
//     register prefetch of next K/V tile, XOR-swizzled V^T layout (kills the
//     8-way bank conflict; stride-136 padding could not - any 16B-aligned
//     stride has words%4==0 so 8*stride_words%32==0).

#define B_ 2
#define S_ 2048
#define D_ 1024
#define H_ 16
#define DH 64
#define M_TILE 64    // queries per block; 16 per wave
#define N_TILE 128   // keys per iteration
#define NITER (S_ / N_TILE)

typedef __bf16 bf16;
typedef __bf16 bf16x4 __attribute__((ext_vector_type(4)));
typedef __bf16 bf16x8 __attribute__((ext_vector_type(8)));
typedef float floatx4 __attribute__((ext_vector_type(4)));

#define K_STRIDE 72    // 144B rows: 16B-aligned, read/write banks uniform
#define V_STRIDE 128   // exact; XOR swizzle key^(f&56) gives uniform banks
#define P_STRIDE 136   // 272B rows: 16B-aligned, banks uniform
#define K_BYTES (128 * K_STRIDE * 2)          // 18432
#define V_BYTES (64 * V_STRIDE * 2)           // 16384
#define P_BYTES (4 * 16 * P_STRIDE * 2)       // 17408 (4 waves x 16 queries)

__device__ __forceinline__ float fast_exp2(float x) {
#if __has_builtin(__builtin_amdgcn_exp2f)
  return __builtin_amdgcn_exp2f(x);
#else
  return exp2f(x);
#endif
}

__global__ __launch_bounds__(256, 3)
void attn_fwd(const float* __restrict__ Qg, const float* __restrict__ Kg,
              const float* __restrict__ Vg, float* __restrict__ Og) {
  __shared__ __align__(16) unsigned char smem[K_BYTES + V_BYTES + P_BYTES];
  bf16* Ksh = (bf16*)smem;                          // [key][feat] stride 72
  bf16* Vsh = (bf16*)(smem + K_BYTES);              // [feat][key^swz] stride 128
  bf16* Psh = (bf16*)(smem + K_BYTES + V_BYTES);    // per-wave [query][key] stride 136

  const int tid  = threadIdx.x;
  const int lane = tid & 63;
  const int wave = tid >> 6;
  const int col  = lane & 15;   // query index (n of S^T MFMA, m of V-frag tiles)
  const int quad = lane >> 4;

  const int bid      = blockIdx.x;
  const int head_lin = bid & 31;   // same head -> same bid%8 -> same XCD
  const int qtile    = bid >> 5;   // 0..31
  const int b        = head_lin >> 4;
  const int h        = head_lin & 15;

  const float QSCALE = 0.125f * 1.44269504088896340736f;  // scale * log2(e)

  // ---- Q fragments (B-operand of S^T = K*Q^T), persistent ----
  bf16x8 Qf[2];
  {
    const int qrow = qtile * M_TILE + wave * 16 + col;
    const float* base = Qg + (size_t)(b * S_ + qrow) * D_ + h * DH + quad * 8;
#pragma unroll
    for (int ks = 0; ks < 2; ++ks) {
      const float4* p = (const float4*)(base + ks * 32);
      float4 x0 = p[0], x1 = p[1];
      bf16x8 f;
      f[0] = (bf16)(x0.x * QSCALE); f[1] = (bf16)(x0.y * QSCALE);
      f[2] = (bf16)(x0.z * QSCALE); f[3] = (bf16)(x0.w * QSCALE);
      f[4] = (bf16)(x1.x * QSCALE); f[5] = (bf16)(x1.y * QSCALE);
      f[6] = (bf16)(x1.z * QSCALE); f[7] = (bf16)(x1.w * QSCALE);
      Qf[ks] = f;
    }
  }

  floatx4 accS[8];       // S^T: key = kt*16 + quad*4 + r, query = col
  floatx4 accO[4];       // O^T: feat = ft*16 + quad*4 + r, query = col
  float m_run = -1e30f, l_run = 0.f;
#pragma unroll
  for (int ft = 0; ft < 4; ++ft) accO[ft] = (floatx4)0.f;

  const float* Kbase = Kg + (size_t)(b * S_) * D_ + h * DH;
  const float* Vbase = Vg + (size_t)(b * S_) * D_ + h * DH;

  // staging geometry (per thread)
  const int krow0 = tid >> 4;        // + 16*i
  const int kf4   = tid & 15;
  const int vr0   = (tid >> 3) << 2; // 4-key group, 0..124
  const int vf0   = (tid & 7) << 3;  // 8-feat group, 0..56

  // ---- prologue: stage tile 0 ----
  {
#pragma unroll
    for (int i = 0; i < 8; ++i) {
      float4 x = *(const float4*)(Kbase + (size_t)(krow0 + 16 * i) * D_ + kf4 * 4);
      bf16x4 y = {(bf16)x.x, (bf16)x.y, (bf16)x.z, (bf16)x.w};
      *(bf16x4*)(Ksh + (krow0 + 16 * i) * K_STRIDE + kf4 * 4) = y;
    }
    float vals[4][8];
#pragma unroll
    for (int rr = 0; rr < 4; ++rr) {
      const float* vp = Vbase + (size_t)(vr0 + rr) * D_ + vf0;
      float4 a = *(const float4*)vp;
      float4 c = *(const float4*)(vp + 4);
      vals[rr][0] = a.x; vals[rr][1] = a.y; vals[rr][2] = a.z; vals[rr][3] = a.w;
      vals[rr][4] = c.x; vals[rr][5] = c.y; vals[rr][6] = c.z; vals[rr][7] = c.w;
    }
#pragma unroll
    for (int j = 0; j < 8; ++j) {
      bf16x4 y = {(bf16)vals[0][j], (bf16)vals[1][j], (bf16)vals[2][j], (bf16)vals[3][j]};
      *(bf16x4*)(Vsh + (vf0 + j) * V_STRIDE + (vr0 ^ vf0)) = y;  // (f&56)==vf0
    }
  }
  __syncthreads();

  bf16* Pw = Psh + wave * (16 * P_STRIDE);

  for (int it = 0; it < NITER; ++it) {
    // ---- prefetch next tile into registers (latency hidden by compute) ----
    const int kb_next = ((it + 1) & (NITER - 1)) * N_TILE;
    float4 kf[8];
#pragma unroll
    for (int i = 0; i < 8; ++i)
      kf[i] = *(const float4*)(Kbase + (size_t)(kb_next + krow0 + 16 * i) * D_ + kf4 * 4);
    float4 vf[8];
#pragma unroll
    for (int rr = 0; rr < 4; ++rr) {
      const float* vp = Vbase + (size_t)(kb_next + vr0 + rr) * D_ + vf0;
      vf[rr * 2]     = *(const float4*)vp;
      vf[rr * 2 + 1] = *(const float4*)(vp + 4);
    }

    // ---- S^T = K * Q^T ----
#pragma unroll
    for (int kt = 0; kt < 8; ++kt) {
      bf16x8 Ka0 = *(bf16x8*)(Ksh + (kt * 16 + col) * K_STRIDE + quad * 8);
      bf16x8 Ka1 = *(bf16x8*)(Ksh + (kt * 16 + col) * K_STRIDE + 32 + quad * 8);
      floatx4 acc = (floatx4)0.f;
      acc = __builtin_amdgcn_mfma_f32_16x16x32_bf16(Ka0, Qf[0], acc, 0, 0, 0);
      acc = __builtin_amdgcn_mfma_f32_16x16x32_bf16(Ka1, Qf[1], acc, 0, 0, 0);
      accS[kt] = acc;
    }

    // ---- online softmax (exp2 domain) ----
    {
      float mx = accS[0][0];
#pragma unroll
      for (int kt = 0; kt < 8; ++kt)
#pragma unroll
        for (int r = 0; r < 4; ++r) mx = fmaxf(mx, accS[kt][r]);
      mx = fmaxf(mx, __shfl_xor(mx, 16));
      mx = fmaxf(mx, __shfl_xor(mx, 32));
      const float mn = fmaxf(m_run, mx);
      const float al = fast_exp2(m_run - mn);
      m_run = mn;
      float rs = 0.f;
#pragma unroll
      for (int kt = 0; kt < 8; ++kt)
#pragma unroll
        for (int r = 0; r < 4; ++r) {
          float p = fast_exp2(accS[kt][r] - mn);
          accS[kt][r] = p;
          rs += p;
        }
      rs += __shfl_xor(rs, 16);
      rs += __shfl_xor(rs, 32);
      l_run = l_run * al + rs;
#pragma unroll
      for (int ft = 0; ft < 4; ++ft) accO[ft] *= al;
    }

    // ---- P -> wave-local LDS (bf16) ----
#pragma unroll
    for (int kt = 0; kt < 8; ++kt) {
      floatx4 p = accS[kt];
      bf16x4 pk = {(bf16)p[0], (bf16)p[1], (bf16)p[2], (bf16)p[3]};
      *(bf16x4*)(Pw + col * P_STRIDE + kt * 16 + quad * 4) = pk;
    }
    __asm__ volatile("s_waitcnt lgkmcnt(0)" ::: "memory");  // wave-local RAW

    // ---- O^T += V^T * P^T ----
#pragma unroll
    for (int ks = 0; ks < 4; ++ks) {
      bf16x8 Pf = *(bf16x8*)(Pw + col * P_STRIDE + ks * 32 + quad * 8);
#pragma unroll
      for (int ft = 0; ft < 4; ++ft) {
        const int f = ft * 16 + col;
        bf16x8 Vf = *(bf16x8*)(Vsh + f * V_STRIDE + ((ks * 32 + quad * 8) ^ (f & 56)));
        accO[ft] = __builtin_amdgcn_mfma_f32_16x16x32_bf16(Vf, Pf, accO[ft], 0, 0, 0);
      }
    }

    __syncthreads();  // everyone done reading Ksh/Vsh

    // ---- write prefetched tile to LDS ----
#pragma unroll
    for (int i = 0; i < 8; ++i) {
      float4 x = kf[i];
      bf16x4 y = {(bf16)x.x, (bf16)x.y, (bf16)x.z, (bf16)x.w};
      *(bf16x4*)(Ksh + (krow0 + 16 * i) * K_STRIDE + kf4 * 4) = y;
    }
#pragma unroll
    for (int j = 0; j < 8; ++j) {
      float4 lo = vf[(j >> 2)];  // placeholder, replaced below
      (void)lo;
    }
    {
      // vf[rr*2] holds feats vf0..vf0+3, vf[rr*2+1] feats vf0+4..vf0+7, key vr0+rr
      float vals[4][8];
#pragma unroll
      for (int rr = 0; rr < 4; ++rr) {
        vals[rr][0] = vf[rr * 2].x; vals[rr][1] = vf[rr * 2].y;
        vals[rr][2] = vf[rr * 2].z; vals[rr][3] = vf[rr * 2].w;
        vals[rr][4] = vf[rr * 2 + 1].x; vals[rr][5] = vf[rr * 2 + 1].y;
        vals[rr][6] = vf[rr * 2 + 1].z; vals[rr][7] = vf[rr * 2 + 1].w;
      }
#pragma unroll
      for (int j = 0; j < 8; ++j) {
        bf16x4 y = {(bf16)vals[0][j], (bf16)vals[1][j], (bf16)vals[2][j], (bf16)vals[3][j]};
        *(bf16x4*)(Vsh + (vf0 + j) * V_STRIDE + (vr0 ^ vf0)) = y;
      }
    }
    __syncthreads();  // staged tile visible
  }

  // ---- epilogue: O = O^T / l ----
  const float rl = 1.0f / l_run;
  const int qrow = qtile * M_TILE + wave * 16 + col;
#pragma unroll
  for (int ft = 0; ft < 4; ++ft) {
    float* dst = Og + (size_t)(b * S_ + qrow) * D_ + h * DH + ft * 16 + quad * 4;
    *(floatx4*)dst = accO[ft] * rl;
  }
}

extern "C" void kernel_launch(void* const* d_in, const int* in_sizes, int n_in,
                              void* d_out, int out_size, void* d_ws, size_t ws_size,
                              hipStream_t stream) {
  const float* Q = (const float*)d_in[0];
  const float* K = (const float*)d_in[1];
  const float* V = (const float*)d_in[2];
  float* O = (float*)d_out;
  dim3 grid(B_ * H_ * (S_ / M_TILE));   // 1024 blocks
  dim3 block(256);
  hipLaunchKernelGGL(attn_fwd, grid, block, 0, stream, Q, K, V, O);
}